// Round 7
// baseline (47.099 us; speedup 1.0000x reference)
//
#include <hip/hip_runtime.h>
#include <math.h>

#define NF   640
#define IMGN 256
#define NPIX (IMGN * IMGN)
#define TEXN 6
#define TPB  512            // 8 waves
#define NCH  8              // face chunks == waves
#define CHF  (NF / NCH)     // 80 faces per chunk
#define PPL  4              // pixels per lane (64 lanes * 4 = 256 = one row)

// Single fused kernel, grid = 256 blocks (one per image ROW), 512 threads.
// Wave w: computes records for its 80-face chunk (regs -> LDS), culls
// against the row (conservative bbox), ballot-compacts survivors ascending,
// then rasterizes ~20 candidates for all 256 row pixels (4 per lane).
// Per-pixel argmin-merge across the 8 chunks -> shade -> write.
//
// CORRECTNESS CONTRACT (bit-exact vs numpy f32 ref, verified R2-R6):
//  - fp contract OFF, true IEEE '/', identical op order on decision path
//  - sign gate == post-division w>=0 test (IEEE sign rules)
//  - bbox cull conservative (pad (ext+1)*1e-6 >> ~ext*2^-23 accept slack);
//    degenerate faces never listed == det_ok mask
//  - chunk-ascending traversal + strict '<' merge == jnp.argmin
//    first-occurrence
//  - hoisted products (qy*ex, dx*qy) are the identical mul/sub trees
__global__ __launch_bounds__(TPB) void render_kernel(
    const float* __restrict__ verts,   // 400*3 f32
    const int*   __restrict__ faces,   // 640*3 i32
    const float* __restrict__ tex,     // 640*6*6*6*3 f32
    float* __restrict__ out)           // 3*65536 f32 (planar CHW)
{
#pragma clang fp contract(off)
    __shared__ float4 fAB[NF * 2];            // 20480 B
    __shared__ float4 fC[NF];                 // 10240 B
    __shared__ unsigned short sList[NCH][CHF];//  1280 B
    __shared__ float rD[NCH][IMGN];           //  8192 B
    __shared__ int   rI[NCH][IMGN];           //  8192 B  (total 48384 B)

    const float EPSf = 1e-8f;
    const int tid  = (int)threadIdx.x;
    const int wid  = tid >> 6;
    const int lane = tid & 63;
    const int row  = (int)blockIdx.x;

    const float by    = -(((row + 0.5f) / (float)IMGN) * 2.0f - 1.0f);
    const float bxmin = ((0   + 0.5f) / (float)IMGN) * 2.0f - 1.0f;
    const float bxmax = ((255 + 0.5f) / (float)IMGN) * 2.0f - 1.0f;

    // ---- fused setup + cull: wave w owns faces [80w, 80w+80) ----
    const int fbeg = wid * CHF;
    int cnt = 0;
    for (int r = 0; r < 2; ++r) {
        int idx = r * 64 + lane;
        int f = fbeg + idx;
        bool pred = false;
        if (idx < CHF) {
            int ia = faces[3 * f + 0];
            int ib = faces[3 * f + 1];
            int ic = faces[3 * f + 2];
            float ax = verts[3 * ia], ay = verts[3 * ia + 1], az = verts[3 * ia + 2];
            float bx = verts[3 * ib], byy = verts[3 * ib + 1], bz = verts[3 * ib + 2];
            float cx = verts[3 * ic], cy = verts[3 * ic + 1], cz = verts[3 * ic + 2];

            // lighting (value-only path)
            float e1x = bx - ax, e1y = byy - ay, e1z = bz - az;
            float e2x = cx - ax, e2y = cy - ay, e2z = cz - az;
            float nx = e1y * e2z - e1z * e2y;
            float ny = e1z * e2x - e1x * e2z;
            float nz = e1x * e2y - e1y * e2x;
            float nn = sqrtf((nx * nx + ny * ny) + nz * nz) + EPSf;
            float diff = nz / nn;
            diff = diff > 0.0f ? diff : 0.0f;
            float light = 0.5f + 0.5f * diff;

            // project: vc = [x, y, z+2], wfov == 1.0f exactly
            float z0 = az + 2.0f, z1 = bz + 2.0f, z2 = cz + 2.0f;
            float den0 = z0 * 1.0f + EPSf;
            float den1 = z1 * 1.0f + EPSf;
            float den2 = z2 * 1.0f + EPSf;
            float px0 = ax / den0, py0 = ay / den0;
            float px1 = bx / den1, py1 = byy / den1;
            float px2 = cx / den2, py2 = cy / den2;

            float dx = px1 - px0, dy = py1 - py0;
            float ex = px2 - px0, ey = py2 - py0;
            float det = dx * ey - dy * ex;
            bool ok = fabsf(det) > 1e-8f;

            fAB[2 * f]     = make_float4(px0, py0, ex, ey);
            fAB[2 * f + 1] = make_float4(dx, dy, ok ? det : 1.0f, z0);
            fC[f]          = make_float4(z1, z2, light, 0.0f);

            if (ok) {
                float xmin = fminf(px0, fminf(px1, px2));
                float xmax = fmaxf(px0, fmaxf(px1, px2));
                float ymin = fminf(py0, fminf(py1, py2));
                float ymax = fmaxf(py0, fmaxf(py1, py2));
                float padx = (fmaxf(fabsf(xmin), fabsf(xmax)) + 1.0f) * 1e-6f;
                float pady = (fmaxf(fabsf(ymin), fabsf(ymax)) + 1.0f) * 1e-6f;
                pred = (ymin - pady <= by)    && (ymax + pady >= by) &&
                       (xmin - padx <= bxmax) && (xmax + padx >= bxmin);
            }
        }
        unsigned long long m = __ballot(pred);
        if (pred)
            sList[wid][cnt + (int)__popcll(m & ((1ull << lane) - 1ull))] =
                (unsigned short)f;
        cnt += (int)__popcll(m);
    }
    __syncthreads();

    // ---- raster: each lane owns 4 pixels (cols lane, lane+64, ...) ----
    float ppx[PPL];
    float best[PPL];
    int   bi[PPL];
    #pragma unroll
    for (int k = 0; k < PPL; ++k) {
        ppx[k]  = ((lane + 64 * k + 0.5f) / (float)IMGN) * 2.0f - 1.0f;
        best[k] = 1e30f;
        bi[k]   = -1;
    }

    for (int kk = 0; kk < cnt; ++kk) {
        int f = (int)sList[wid][kk];
        float4 a = fAB[2 * f];        // v0x v0y ex ey
        float4 b = fAB[2 * f + 1];    // dx dy det z0
        float4 c = fC[f];             // z1 z2 light
        float qy  = by - a.y;         // row-uniform
        float t1  = qy * a.z;         // qy*ex (shared mul, same bits)
        float t2  = b.x * qy;         // dx*qy (shared mul, same bits)
        #pragma unroll
        for (int k = 0; k < PPL; ++k) {
            float qx = ppx[k] - a.x;
            float n1 = qx * a.w - t1;
            float n2 = t2 - b.y * qx;
            // sign gate == (w1>=0 && w2>=0) after IEEE division
            bool pass = (b.z > 0.0f) ? (n1 >= 0.0f && n2 >= 0.0f)
                                     : (n1 <= 0.0f && n2 <= 0.0f);
            if (pass) {
                float w1 = n1 / b.z;
                float w2 = n2 / b.z;
                float w0 = (1.0f - w1) - w2;
                if (w0 >= 0.0f) {
                    float depth = ((w0 * b.w) + (w1 * c.x)) + (w2 * c.y);
                    if (depth > 0.0f && depth < best[k]) {
                        best[k] = depth; bi[k] = f;
                    }
                }
            }
        }
    }

    #pragma unroll
    for (int k = 0; k < PPL; ++k) {
        rD[wid][lane + 64 * k] = best[k];
        rI[wid][lane + 64 * k] = bi[k];
    }
    __syncthreads();

    // ---- waves 0-3: per-pixel argmin-merge, recompute w, shade, write ----
    if (tid < IMGN) {
        float bd = rD[0][tid];
        int   fi = rI[0][tid];
        for (int cc = 1; cc < NCH; ++cc) {
            float d = rD[cc][tid];
            if (d < bd) { bd = d; fi = rI[cc][tid]; }  // ascending, strict <
        }

        int pp = row * IMGN + tid;
        float r = 0.0f, g = 0.0f, b = 0.0f;
        if (fi >= 0) {
            // recompute barycentrics: identical ops on identical LDS bits
            float4 a2 = fAB[2 * fi];
            float4 b2 = fAB[2 * fi + 1];
            float sx = ((tid + 0.5f) / (float)IMGN) * 2.0f - 1.0f;
            float qx = sx - a2.x;
            float qy = by - a2.y;
            float n1 = qx * a2.w - qy * a2.z;
            float n2 = b2.x * qy - b2.y * qx;
            float w1 = n1 / b2.z;
            float w2 = n2 / b2.z;
            float w0 = (1.0f - w1) - w2;

            int i0 = (int)(w0 * (float)TEXN);
            int i1 = (int)(w1 * (float)TEXN);
            int i2 = (int)(w2 * (float)TEXN);
            i0 = i0 < 0 ? 0 : (i0 > TEXN - 1 ? TEXN - 1 : i0);
            i1 = i1 < 0 ? 0 : (i1 > TEXN - 1 ? TEXN - 1 : i1);
            i2 = i2 < 0 ? 0 : (i2 > TEXN - 1 ? TEXN - 1 : i2);
            const float* tp = tex + (size_t)((((fi * TEXN + i0) * TEXN + i1) * TEXN + i2) * 3);
            float light = fC[fi].z;
            r = tanhf(tp[0]) * light;
            g = tanhf(tp[1]) * light;
            b = tanhf(tp[2]) * light;
        }
        out[pp]            = r;
        out[NPIX + pp]     = g;
        out[2 * NPIX + pp] = b;
    }
}

extern "C" void kernel_launch(void* const* d_in, const int* in_sizes, int n_in,
                              void* d_out, int out_size, void* d_ws, size_t ws_size,
                              hipStream_t stream) {
    (void)in_sizes; (void)n_in; (void)d_ws; (void)ws_size; (void)out_size;
    const float* verts = (const float*)d_in[0];
    const int*   faces = (const int*)d_in[1];
    const float* tex   = (const float*)d_in[2];
    float*       out   = (float*)d_out;
    render_kernel<<<IMGN, TPB, 0, stream>>>(verts, faces, tex, out);
}

// Round 8
// 28.699 us; speedup vs baseline: 1.6412x; 1.6412x over previous
//
#include <hip/hip_runtime.h>
#include <math.h>

#define NF   640
#define IMGN 256
#define NPIX (IMGN * IMGN)
#define TEXN 6
#define TPB  512            // 8 waves
#define PXW  64             // pixels per block (row segment)
#define NCH  8              // face chunks == waves
#define CHF  (NF / NCH)     // 80 faces per chunk

// Block = 64 consecutive pixels of one row; 8 waves each own an 80-face
// chunk: fused setup (regs->LDS) + conservative bbox cull + ballot-compact
// (ascending), then rasterize ~10 candidates for the 64 pixels from LDS.
// Tail: transposed LDS scoreboard + 8-lane-group shfl argmin-reduce
// ((depth, face) lexicographic == jnp.argmin first-occurrence), shade
// spread across all 8 waves.
//
// CORRECTNESS CONTRACT (bit-exact vs numpy f32 ref, verified R2-R7):
//  - fp contract OFF, true IEEE '/', identical op order on decision path
//  - sign gate == post-division w>=0 test (IEEE sign rules)
//  - bbox cull conservative (pad (ext+1)*1e-6 >> ~ext*2^-23 accept slack);
//    degenerate faces never listed == det_ok mask
//  - chunk-ascending lists + lexicographic (depth, face) reduce ==
//    first-occurrence argmin over original face order
//  - shade recomputes w with identical ops on identical LDS bits
__global__ __launch_bounds__(TPB) void render_kernel(
    const float* __restrict__ verts,   // 400*3 f32
    const int*   __restrict__ faces,   // 640*3 i32
    const float* __restrict__ tex,     // 640*6*6*6*3 f32
    float* __restrict__ out)           // 3*65536 f32 (planar CHW)
{
#pragma clang fp contract(off)
    __shared__ float4 fAB[NF * 2];            // 20480 B
    __shared__ float4 fC[NF];                 // 10240 B
    __shared__ unsigned short sList[NCH][CHF];//  1280 B
    __shared__ float rD[PXW][NCH];            //  2048 B (transposed)
    __shared__ int   rI[PXW][NCH];            //  2048 B  => 36096 B total

    const float EPSf = 1e-8f;
    const int tid  = (int)threadIdx.x;
    const int wid  = tid >> 6;
    const int lane = tid & 63;
    const int p0   = (int)blockIdx.x * PXW;
    const int pi   = p0 >> 8;          // row (uniform per block)
    const int pj0  = p0 & (IMGN - 1);  // first col

    const float by    = -(((pi + 0.5f) / (float)IMGN) * 2.0f - 1.0f);
    const float bxmin = ((pj0 + 0.5f) / (float)IMGN) * 2.0f - 1.0f;
    const float bxmax = ((pj0 + (PXW - 1) + 0.5f) / (float)IMGN) * 2.0f - 1.0f;

    // ---- fused setup + cull: wave w owns faces [80w, 80w+80) ----
    const int fbeg = wid * CHF;
    int cnt = 0;
    for (int r = 0; r < 2; ++r) {
        int idx = r * 64 + lane;
        int f = fbeg + idx;
        bool pred = false;
        if (idx < CHF) {
            int ia = faces[3 * f + 0];
            int ib = faces[3 * f + 1];
            int ic = faces[3 * f + 2];
            float ax = verts[3 * ia], ay = verts[3 * ia + 1], az = verts[3 * ia + 2];
            float bx = verts[3 * ib], byy = verts[3 * ib + 1], bz = verts[3 * ib + 2];
            float cx = verts[3 * ic], cy = verts[3 * ic + 1], cz = verts[3 * ic + 2];

            // lighting (value-only path)
            float e1x = bx - ax, e1y = byy - ay, e1z = bz - az;
            float e2x = cx - ax, e2y = cy - ay, e2z = cz - az;
            float nx = e1y * e2z - e1z * e2y;
            float ny = e1z * e2x - e1x * e2z;
            float nz = e1x * e2y - e1y * e2x;
            float nn = sqrtf((nx * nx + ny * ny) + nz * nz) + EPSf;
            float diff = nz / nn;
            diff = diff > 0.0f ? diff : 0.0f;
            float light = 0.5f + 0.5f * diff;

            // project: vc = [x, y, z+2], wfov == 1.0f exactly
            float z0 = az + 2.0f, z1 = bz + 2.0f, z2 = cz + 2.0f;
            float den0 = z0 * 1.0f + EPSf;
            float den1 = z1 * 1.0f + EPSf;
            float den2 = z2 * 1.0f + EPSf;
            float px0 = ax / den0, py0 = ay / den0;
            float px1 = bx / den1, py1 = byy / den1;
            float px2 = cx / den2, py2 = cy / den2;

            float dx = px1 - px0, dy = py1 - py0;
            float ex = px2 - px0, ey = py2 - py0;
            float det = dx * ey - dy * ex;
            bool ok = fabsf(det) > 1e-8f;

            fAB[2 * f]     = make_float4(px0, py0, ex, ey);
            fAB[2 * f + 1] = make_float4(dx, dy, ok ? det : 1.0f, z0);
            fC[f]          = make_float4(z1, z2, light, 0.0f);

            if (ok) {
                float xmin = fminf(px0, fminf(px1, px2));
                float xmax = fmaxf(px0, fmaxf(px1, px2));
                float ymin = fminf(py0, fminf(py1, py2));
                float ymax = fmaxf(py0, fmaxf(py1, py2));
                float padx = (fmaxf(fabsf(xmin), fabsf(xmax)) + 1.0f) * 1e-6f;
                float pady = (fmaxf(fabsf(ymin), fabsf(ymax)) + 1.0f) * 1e-6f;
                pred = (ymin - pady <= by)    && (ymax + pady >= by) &&
                       (xmin - padx <= bxmax) && (xmax + padx >= bxmin);
            }
        }
        unsigned long long m = __ballot(pred);
        if (pred)
            sList[wid][cnt + (int)__popcll(m & ((1ull << lane) - 1ull))] =
                (unsigned short)f;
        cnt += (int)__popcll(m);
    }

    // ---- raster this wave's candidates (LDS broadcast, pipelined idx) ----
    const float ppx = ((pj0 + lane + 0.5f) / (float)IMGN) * 2.0f - 1.0f;
    const float ppy = by;

    float best = 1e30f;
    int   bi = -1;

    int fnext = (cnt > 0) ? (int)sList[wid][0] : 0;
    for (int k = 0; k < cnt; ++k) {
        int f = fnext;
        if (k + 1 < cnt) fnext = (int)sList[wid][k + 1];
        float4 a = fAB[2 * f];        // v0x v0y ex ey
        float4 b = fAB[2 * f + 1];    // dx dy det z0
        float qx = ppx - a.x;
        float qy = ppy - a.y;
        float n1 = qx * a.w - qy * a.z;
        float n2 = b.x * qy - b.y * qx;
        // sign gate == (w1>=0 && w2>=0) after IEEE division, bit-exact
        bool pass = (b.z > 0.0f) ? (n1 >= 0.0f && n2 >= 0.0f)
                                 : (n1 <= 0.0f && n2 <= 0.0f);
        if (pass) {
            float w1 = n1 / b.z;
            float w2 = n2 / b.z;
            float w0 = (1.0f - w1) - w2;
            if (w0 >= 0.0f) {
                float4 c = fC[f];     // z1 z2 light
                float depth = ((w0 * b.w) + (w1 * c.x)) + (w2 * c.y);
                if (depth > 0.0f && depth < best) {
                    best = depth; bi = f;
                }
            }
        }
    }

    rD[lane][wid] = best;
    rI[lane][wid] = bi;
    __syncthreads();

    // ---- parallel tail: wave w reduces+shades pixels [8w, 8w+8) ----
    // lane l: pixel px = 8*wid + (l>>3), chunk c = l&7 (2-way banks, free)
    {
        int px = 8 * wid + (lane >> 3);
        int c  = lane & 7;
        float d  = rD[px][c];
        int   fi = rI[px][c];
        // lexicographic (depth, face) min over the 8-lane group ==
        // first-occurrence argmin (chunk ranges are face-ordered)
        #pragma unroll
        for (int m = 1; m < 8; m <<= 1) {
            float pd  = __shfl_xor(d, m, 64);
            int   pfi = __shfl_xor(fi, m, 64);
            if (pd < d || (pd == d && pfi < fi)) { d = pd; fi = pfi; }
        }

        if ((lane & 7) == 0) {
            int pp = p0 + px;
            float r = 0.0f, g = 0.0f, b = 0.0f;
            if (fi >= 0) {
                // recompute barycentrics: identical ops on identical bits
                float4 a2 = fAB[2 * fi];
                float4 b2 = fAB[2 * fi + 1];
                float sx = ((pj0 + px + 0.5f) / (float)IMGN) * 2.0f - 1.0f;
                float qx = sx - a2.x;
                float qy = by - a2.y;
                float n1 = qx * a2.w - qy * a2.z;
                float n2 = b2.x * qy - b2.y * qx;
                float w1 = n1 / b2.z;
                float w2 = n2 / b2.z;
                float w0 = (1.0f - w1) - w2;

                int i0 = (int)(w0 * (float)TEXN);
                int i1 = (int)(w1 * (float)TEXN);
                int i2 = (int)(w2 * (float)TEXN);
                i0 = i0 < 0 ? 0 : (i0 > TEXN - 1 ? TEXN - 1 : i0);
                i1 = i1 < 0 ? 0 : (i1 > TEXN - 1 ? TEXN - 1 : i1);
                i2 = i2 < 0 ? 0 : (i2 > TEXN - 1 ? TEXN - 1 : i2);
                const float* tp = tex + (size_t)((((fi * TEXN + i0) * TEXN + i1) * TEXN + i2) * 3);
                float light = fC[fi].z;
                r = tanhf(tp[0]) * light;
                g = tanhf(tp[1]) * light;
                b = tanhf(tp[2]) * light;
            }
            out[pp]            = r;
            out[NPIX + pp]     = g;
            out[2 * NPIX + pp] = b;
        }
    }
}

extern "C" void kernel_launch(void* const* d_in, const int* in_sizes, int n_in,
                              void* d_out, int out_size, void* d_ws, size_t ws_size,
                              hipStream_t stream) {
    (void)in_sizes; (void)n_in; (void)d_ws; (void)ws_size; (void)out_size;
    const float* verts = (const float*)d_in[0];
    const int*   faces = (const int*)d_in[1];
    const float* tex   = (const float*)d_in[2];
    float*       out   = (float*)d_out;
    render_kernel<<<NPIX / PXW, TPB, 0, stream>>>(verts, faces, tex, out);
}

// Round 9
// 26.169 us; speedup vs baseline: 1.7998x; 1.0967x over previous
//
#include <hip/hip_runtime.h>
#include <math.h>

#define NF   640
#define IMGN 256
#define NPIX (IMGN * IMGN)
#define TEXN 6
#define TPB  512            // 8 waves
#define PXW  64             // pixels per block (row segment)
#define NCH  8              // face chunks == waves
#define CHF  (NF / NCH)     // 80 faces per chunk

// Block = 64 consecutive pixels of one row; 8 waves each own an 80-face
// chunk: fused setup (NO lighting) + conservative bbox cull +
// ballot-compact (ascending), rasterize ~10 candidates from LDS.
// Tail (wave 0): serial 8-chunk argmin merge (strict '<', chunk-ascending
// == jnp.argmin first-occurrence), winner-only lighting, shade, coalesced
// writes.
//
// CORRECTNESS CONTRACT (bit-exact vs numpy f32 ref, verified R2-R8):
//  - fp contract OFF, true IEEE '/', identical op order on decision path
//  - sign gate == post-division w>=0 test (IEEE sign rules)
//  - bbox cull conservative (pad (ext+1)*1e-6 >> ~ext*2^-23 accept slack);
//    degenerate faces never listed == det_ok mask
//  - lighting moved to tail: same expression order on same vertex bits
//    => same light value; it scales color only (no decisions)
//  - shade recomputes w with identical ops on identical LDS bits
__global__ __launch_bounds__(TPB) void render_kernel(
    const float* __restrict__ verts,   // 400*3 f32
    const int*   __restrict__ faces,   // 640*3 i32
    const float* __restrict__ tex,     // 640*6*6*6*3 f32
    float* __restrict__ out)           // 3*65536 f32 (planar CHW)
{
#pragma clang fp contract(off)
    __shared__ float4 fA[NF];                 // 10240 B {v0x,v0y,ex,ey}
    __shared__ float4 fB[NF];                 // 10240 B {dx,dy,det,z0}
    __shared__ float2 fZ[NF];                 //  5120 B {z1,z2}
    __shared__ unsigned short sList[NCH][CHF];//  1280 B
    __shared__ float rD[NCH][PXW];            //  2048 B
    __shared__ int   rI[NCH][PXW];            //  2048 B  => 30976 B total

    const float EPSf = 1e-8f;
    const int tid  = (int)threadIdx.x;
    const int wid  = tid >> 6;
    const int lane = tid & 63;
    const int p0   = (int)blockIdx.x * PXW;
    const int pi   = p0 >> 8;          // row (uniform per block)
    const int pj0  = p0 & (IMGN - 1);  // first col

    const float by    = -(((pi + 0.5f) / (float)IMGN) * 2.0f - 1.0f);
    const float bxmin = ((pj0 + 0.5f) / (float)IMGN) * 2.0f - 1.0f;
    const float bxmax = ((pj0 + (PXW - 1) + 0.5f) / (float)IMGN) * 2.0f - 1.0f;

    // ---- fused setup + cull (no lighting): wave w owns [80w, 80w+80) ----
    const int fbeg = wid * CHF;
    int cnt = 0;
    for (int r = 0; r < 2; ++r) {
        int idx = r * 64 + lane;
        int f = fbeg + idx;
        bool pred = false;
        if (idx < CHF) {
            int ia = faces[3 * f + 0];
            int ib = faces[3 * f + 1];
            int ic = faces[3 * f + 2];
            float ax = verts[3 * ia], ay = verts[3 * ia + 1], az = verts[3 * ia + 2];
            float bx = verts[3 * ib], byy = verts[3 * ib + 1], bz = verts[3 * ib + 2];
            float cx = verts[3 * ic], cy = verts[3 * ic + 1], cz = verts[3 * ic + 2];

            // project: vc = [x, y, z+2], wfov == 1.0f exactly
            float z0 = az + 2.0f, z1 = bz + 2.0f, z2 = cz + 2.0f;
            float den0 = z0 * 1.0f + EPSf;
            float den1 = z1 * 1.0f + EPSf;
            float den2 = z2 * 1.0f + EPSf;
            float px0 = ax / den0, py0 = ay / den0;
            float px1 = bx / den1, py1 = byy / den1;
            float px2 = cx / den2, py2 = cy / den2;

            float dx = px1 - px0, dy = py1 - py0;
            float ex = px2 - px0, ey = py2 - py0;
            float det = dx * ey - dy * ex;
            bool ok = fabsf(det) > 1e-8f;

            fA[f] = make_float4(px0, py0, ex, ey);
            fB[f] = make_float4(dx, dy, ok ? det : 1.0f, z0);
            fZ[f] = make_float2(z1, z2);

            if (ok) {
                float xmin = fminf(px0, fminf(px1, px2));
                float xmax = fmaxf(px0, fmaxf(px1, px2));
                float ymin = fminf(py0, fminf(py1, py2));
                float ymax = fmaxf(py0, fmaxf(py1, py2));
                float padx = (fmaxf(fabsf(xmin), fabsf(xmax)) + 1.0f) * 1e-6f;
                float pady = (fmaxf(fabsf(ymin), fabsf(ymax)) + 1.0f) * 1e-6f;
                pred = (ymin - pady <= by)    && (ymax + pady >= by) &&
                       (xmin - padx <= bxmax) && (xmax + padx >= bxmin);
            }
        }
        unsigned long long m = __ballot(pred);
        if (pred)
            sList[wid][cnt + (int)__popcll(m & ((1ull << lane) - 1ull))] =
                (unsigned short)f;
        cnt += (int)__popcll(m);
    }

    // ---- raster this wave's candidates (LDS broadcast reads) ----
    const float ppx = ((pj0 + lane + 0.5f) / (float)IMGN) * 2.0f - 1.0f;
    const float ppy = by;

    float best = 1e30f;
    int   bi = -1;

    for (int k = 0; k < cnt; ++k) {
        int f = (int)sList[wid][k];
        float4 a = fA[f];             // v0x v0y ex ey
        float4 b = fB[f];             // dx dy det z0
        float qx = ppx - a.x;
        float qy = ppy - a.y;
        float n1 = qx * a.w - qy * a.z;
        float n2 = b.x * qy - b.y * qx;
        // sign gate == (w1>=0 && w2>=0) after IEEE division, bit-exact
        bool pass = (b.z > 0.0f) ? (n1 >= 0.0f && n2 >= 0.0f)
                                 : (n1 <= 0.0f && n2 <= 0.0f);
        if (pass) {
            float w1 = n1 / b.z;
            float w2 = n2 / b.z;
            float w0 = (1.0f - w1) - w2;
            if (w0 >= 0.0f) {
                float2 zz = fZ[f];    // z1 z2
                float depth = ((w0 * b.w) + (w1 * zz.x)) + (w2 * zz.y);
                if (depth > 0.0f && depth < best) {
                    best = depth; bi = f;
                }
            }
        }
    }

    rD[wid][lane] = best;
    rI[wid][lane] = bi;
    __syncthreads();

    // ---- wave 0: merge 8 chunks, winner lighting, shade, write ----
    if (tid < PXW) {
        float bd = rD[0][tid];
        int   fi = rI[0][tid];
        for (int c = 1; c < NCH; ++c) {
            float d = rD[c][tid];
            if (d < bd) { bd = d; fi = rI[c][tid]; }  // ascending, strict <
        }

        int pp = p0 + tid;
        float r = 0.0f, g = 0.0f, b = 0.0f;
        if (fi >= 0) {
            // recompute barycentrics: identical ops on identical LDS bits
            float4 a2 = fA[fi];
            float4 b2 = fB[fi];
            float sx = ((pj0 + tid + 0.5f) / (float)IMGN) * 2.0f - 1.0f;
            float qx = sx - a2.x;
            float qy = by - a2.y;
            float n1 = qx * a2.w - qy * a2.z;
            float n2 = b2.x * qy - b2.y * qx;
            float w1 = n1 / b2.z;
            float w2 = n2 / b2.z;
            float w0 = (1.0f - w1) - w2;

            // winner-only lighting: identical expression on identical bits
            int ia = faces[3 * fi + 0];
            int ib = faces[3 * fi + 1];
            int ic = faces[3 * fi + 2];
            float ax = verts[3 * ia], ay = verts[3 * ia + 1], az = verts[3 * ia + 2];
            float bx = verts[3 * ib], byv = verts[3 * ib + 1], bz = verts[3 * ib + 2];
            float cx = verts[3 * ic], cy = verts[3 * ic + 1], cz = verts[3 * ic + 2];
            float e1x = bx - ax, e1y = byv - ay, e1z = bz - az;
            float e2x = cx - ax, e2y = cy - ay, e2z = cz - az;
            float nx = e1y * e2z - e1z * e2y;
            float ny = e1z * e2x - e1x * e2z;
            float nz = e1x * e2y - e1y * e2x;
            float nn = sqrtf((nx * nx + ny * ny) + nz * nz) + EPSf;
            float diff = nz / nn;
            diff = diff > 0.0f ? diff : 0.0f;
            float light = 0.5f + 0.5f * diff;

            int i0 = (int)(w0 * (float)TEXN);
            int i1 = (int)(w1 * (float)TEXN);
            int i2 = (int)(w2 * (float)TEXN);
            i0 = i0 < 0 ? 0 : (i0 > TEXN - 1 ? TEXN - 1 : i0);
            i1 = i1 < 0 ? 0 : (i1 > TEXN - 1 ? TEXN - 1 : i1);
            i2 = i2 < 0 ? 0 : (i2 > TEXN - 1 ? TEXN - 1 : i2);
            const float* tp = tex + (size_t)((((fi * TEXN + i0) * TEXN + i1) * TEXN + i2) * 3);
            r = tanhf(tp[0]) * light;
            g = tanhf(tp[1]) * light;
            b = tanhf(tp[2]) * light;
        }
        out[pp]            = r;
        out[NPIX + pp]     = g;
        out[2 * NPIX + pp] = b;
    }
}

extern "C" void kernel_launch(void* const* d_in, const int* in_sizes, int n_in,
                              void* d_out, int out_size, void* d_ws, size_t ws_size,
                              hipStream_t stream) {
    (void)in_sizes; (void)n_in; (void)d_ws; (void)ws_size; (void)out_size;
    const float* verts = (const float*)d_in[0];
    const int*   faces = (const int*)d_in[1];
    const float* tex   = (const float*)d_in[2];
    float*       out   = (float*)d_out;
    render_kernel<<<NPIX / PXW, TPB, 0, stream>>>(verts, faces, tex, out);
}